// Round 2
// baseline (1175.651 us; speedup 1.0000x reference)
//
#include <hip/hip_runtime.h>

// AttDownsample: x [32,768,56,56] f32 -> y [32,768,28,28] f32
// q = 3x3 avgpool(stride2,pad1); scores_k = (1/3) q . w_k; softmax over 9; y = sum attn_k w_k
// One block per (n, ho): stage [27ch x 3row x 57col] LDS tiles per channel chunk,
// phase 1 accumulates scores, phase 2 re-reads tiles (L3-warm) for the merge.

constexpr int N_  = 32;
constexpr int C_  = 768;
constexpr int H_  = 56;
constexpr int W_  = 56;
constexpr int HO_ = 28;
constexpr int WO_ = 28;

constexpr int CB      = 27;                    // channels per chunk
constexpr int NCHUNK  = (C_ + CB - 1) / CB;    // 29 (last chunk: 12 real channels)
constexpr int TILE_W  = 57;                    // col -1..55 -> tcol 0..56
constexpr int TILE_ELEMS = CB * 3 * 56;        // 4536 real loads per chunk
constexpr int NLOAD   = (TILE_ELEMS + 255) / 256;  // 18 staging iterations
constexpr int LDS_TILE   = CB * 3 * TILE_W;    // 4617 floats

__global__ __launch_bounds__(256)
void attdown_kernel(const float* __restrict__ x, float* __restrict__ out) {
    const int tid = threadIdx.x;
    const int nho = blockIdx.x;          // 0..895
    const int n   = nho / HO_;
    const int ho  = nho - n * HO_;
    const int wo  = tid % WO_;           // 0..27
    const int cg  = tid / WO_;           // 0..9, active cg<9 (3 channels each)
    const int row0 = 2 * ho - 1;         // top window row (may be -1 -> zero pad)

    __shared__ float tile[LDS_TILE];          // [c][r][tcol]
    __shared__ float sred[9 * WO_ * 9];       // [cg][wo][k]
    __shared__ float attn_s[WO_ * 9];         // [wo][k]

    // ---- precompute per-thread load decomposition (chunk-invariant) ----
    int  goff[NLOAD];        // offset within sample: c*H*W + (row0+r)*W + col
    int  loff[NLOAD];        // LDS offset
    bool active[NLOAD];      // idx < TILE_ELEMS
    bool rowok[NLOAD];       // row0 + r >= 0
#pragma unroll
    for (int i = 0; i < NLOAD; ++i) {
        int idx = i * 256 + tid;
        int c   = idx / 168;             // 168 = 3*56
        int rem = idx - c * 168;
        int r   = rem / 56;
        int col = rem - r * 56;
        active[i] = (idx < TILE_ELEMS);
        rowok[i]  = (row0 + r) >= 0;
        goff[i]   = c * (H_ * W_) + (row0 + r) * W_ + col;
        loff[i]   = (c * 3 + r) * TILE_W + col + 1;
    }

    const float* xb = x + (size_t)n * (C_ * H_ * W_);

    float sacc[9];
#pragma unroll
    for (int k = 0; k < 9; ++k) sacc[k] = 0.f;

    // ================= Phase 1: scores =================
    for (int ch = 0; ch < NCHUNK; ++ch) {
        const int cbase = ch * CB * (H_ * W_);
        if (tid < CB * 3) tile[tid * TILE_W] = 0.f;   // ghost col (col = -1)
#pragma unroll
        for (int i = 0; i < NLOAD; ++i) {
            if (active[i]) {
                float v = 0.f;
                int gidx = cbase + goff[i];
                if (rowok[i] && gidx < C_ * H_ * W_) v = xb[gidx];
                tile[loff[i]] = v;
            }
        }
        __syncthreads();

        if (cg < 9) {
            const int tb = 2 * wo;
#pragma unroll
            for (int j = 0; j < 3; ++j) {
                const float* tp = &tile[(cg * 3 + j) * (3 * TILE_W) + tb];
                float w0 = tp[0],          w1 = tp[1],          w2 = tp[2];
                float w3 = tp[TILE_W],     w4 = tp[TILE_W+1],   w5 = tp[TILE_W+2];
                float w6 = tp[2*TILE_W],   w7 = tp[2*TILE_W+1], w8 = tp[2*TILE_W+2];
                float q = (w0+w1+w2+w3+w4+w5+w6+w7+w8) * (1.f/9.f);
                sacc[0] += q*w0; sacc[1] += q*w1; sacc[2] += q*w2;
                sacc[3] += q*w3; sacc[4] += q*w4; sacc[5] += q*w5;
                sacc[6] += q*w6; sacc[7] += q*w7; sacc[8] += q*w8;
            }
        }
        __syncthreads();
    }

    // ---- reduce partial scores across cg, softmax per wo ----
    if (cg < 9) {
#pragma unroll
        for (int k = 0; k < 9; ++k) sred[(cg * WO_ + wo) * 9 + k] = sacc[k];
    }
    __syncthreads();

    if (tid < WO_) {
        float s[9];
#pragma unroll
        for (int k = 0; k < 9; ++k) {
            float t = 0.f;
            for (int g = 0; g < 9; ++g) t += sred[(g * WO_ + tid) * 9 + k];
            s[k] = t * (1.f / 3.f);      // q already carries the 1/9
        }
        float m = s[0];
#pragma unroll
        for (int k = 1; k < 9; ++k) m = fmaxf(m, s[k]);
        float denom = 0.f;
#pragma unroll
        for (int k = 0; k < 9; ++k) { s[k] = __expf(s[k] - m); denom += s[k]; }
        float inv = 1.f / denom;
#pragma unroll
        for (int k = 0; k < 9; ++k) attn_s[tid * 9 + k] = s[k] * inv;
    }
    __syncthreads();

    // ================= Phase 2: weighted merge =================
    float a[9];
    if (cg < 9) {
#pragma unroll
        for (int k = 0; k < 9; ++k) a[k] = attn_s[wo * 9 + k];
    }
    float* ob = out + (size_t)n * (C_ * HO_ * WO_) + ho * WO_ + wo;

    for (int ch = 0; ch < NCHUNK; ++ch) {
        const int cbase = ch * CB * (H_ * W_);
        if (tid < CB * 3) tile[tid * TILE_W] = 0.f;
#pragma unroll
        for (int i = 0; i < NLOAD; ++i) {
            if (active[i]) {
                float v = 0.f;
                int gidx = cbase + goff[i];
                if (rowok[i] && gidx < C_ * H_ * W_) v = xb[gidx];
                tile[loff[i]] = v;
            }
        }
        __syncthreads();

        if (cg < 9) {
            const int tb = 2 * wo;
#pragma unroll
            for (int j = 0; j < 3; ++j) {
                const int cgl = ch * CB + cg * 3 + j;
                if (cgl < C_) {
                    const float* tp = &tile[(cg * 3 + j) * (3 * TILE_W) + tb];
                    float y = a[0]*tp[0]        + a[1]*tp[1]          + a[2]*tp[2]
                            + a[3]*tp[TILE_W]   + a[4]*tp[TILE_W+1]   + a[5]*tp[TILE_W+2]
                            + a[6]*tp[2*TILE_W] + a[7]*tp[2*TILE_W+1] + a[8]*tp[2*TILE_W+2];
                    ob[(size_t)cgl * (HO_ * WO_)] = y;
                }
            }
        }
        __syncthreads();
    }
}

extern "C" void kernel_launch(void* const* d_in, const int* in_sizes, int n_in,
                              void* d_out, int out_size, void* d_ws, size_t ws_size,
                              hipStream_t stream) {
    const float* x = (const float*)d_in[0];
    float* out = (float*)d_out;
    attdown_kernel<<<dim3(N_ * HO_), dim3(256), 0, stream>>>(x, out);
}

// Round 3
// 522.363 us; speedup vs baseline: 2.2506x; 2.2506x over previous
//
#include <hip/hip_runtime.h>

// AttDownsample: x [32,768,56,56] f32 -> y [32,768,28,28] f32
// 3-kernel split: (1) partial scores w/ atomicAdd, (2) softmax over k=9, (3) merge.
// ws layout: scores/attn [N,Ho,Wo,9] f32 = 903168 B.

constexpr int N_  = 32;
constexpr int C_  = 768;
constexpr int H_  = 56;
constexpr int W_  = 56;
constexpr int HO_ = 28;
constexpr int WO_ = 28;
constexpr int NPIX = N_ * HO_ * WO_;          // 25088

// ---- kernel 1: scores ----
constexpr int K1_CB     = 16;                  // channels per block
constexpr int K1_NCHUNK = C_ / K1_CB;          // 48 (exact)
constexpr int K1_TW     = 58;                  // row stride in tile (cols 0..55 data, 56..57 zero)
constexpr int K1_TILE   = K1_CB * 3 * K1_TW;   // 2784 floats

__global__ __launch_bounds__(256)
void scores_kernel(const float* __restrict__ x, float* __restrict__ scores) {
    __shared__ float tile_raw[4 + K1_TILE];    // +4 front pad so col -1 reads hit zero, keeps f4 alignment
    __shared__ float sred[8 * WO_ * 9];        // [g][wo][k]
    float* tile = tile_raw + 4;

    const int tid   = threadIdx.x;
    const int blk   = blockIdx.x;
    const int chunk = blk / (N_ * HO_);        // contending blocks (same nho) are 896 apart
    const int nho   = blk % (N_ * HO_);
    const int n     = nho / HO_;
    const int ho    = nho % HO_;
    const int cbase = chunk * K1_CB;
    const int row0  = 2 * ho - 1;

    for (int i = tid; i < 4 + K1_TILE; i += 256) tile_raw[i] = 0.f;
    __syncthreads();

    const float* xb = x + (size_t)n * (C_ * H_ * W_);
    // 16 ch x 3 rows x 14 float4 = 672 vector loads
    for (int i = tid; i < 672; i += 256) {
        int c   = i / 42;
        int rem = i - c * 42;
        int r   = rem / 14;
        int kk  = rem - r * 14;
        int grow = row0 + r;
        if (grow >= 0) {
            float4 v = *(const float4*)(xb + ((size_t)(cbase + c) * H_ + grow) * W_ + 4 * kk);
            float* d = &tile[c * (3 * K1_TW) + r * K1_TW + 4 * kk];
            d[0] = v.x; d[1] = v.y; d[2] = v.z; d[3] = v.w;
        }
    }
    __syncthreads();

    const int wo = tid % WO_;
    const int g  = tid / WO_;                  // 0..9, active g<8, 2 channels each
    if (g < 8) {
        float sacc[9];
#pragma unroll
        for (int k = 0; k < 9; ++k) sacc[k] = 0.f;
#pragma unroll
        for (int cc = 0; cc < 2; ++cc) {
            const float* tp = &tile[(g * 2 + cc) * (3 * K1_TW) + 2 * wo - 1];
            float w0 = tp[0],          w1 = tp[1],            w2 = tp[2];
            float w3 = tp[K1_TW],      w4 = tp[K1_TW + 1],    w5 = tp[K1_TW + 2];
            float w6 = tp[2 * K1_TW],  w7 = tp[2 * K1_TW + 1], w8 = tp[2 * K1_TW + 2];
            float q = (w0 + w1 + w2 + w3 + w4 + w5 + w6 + w7 + w8) * (1.f / 9.f);
            sacc[0] += q * w0; sacc[1] += q * w1; sacc[2] += q * w2;
            sacc[3] += q * w3; sacc[4] += q * w4; sacc[5] += q * w5;
            sacc[6] += q * w6; sacc[7] += q * w7; sacc[8] += q * w8;
        }
#pragma unroll
        for (int k = 0; k < 9; ++k) sred[(g * WO_ + wo) * 9 + k] = sacc[k];
    }
    __syncthreads();

    if (tid < WO_ * 9) {
        int wo2 = tid / 9, k = tid - wo2 * 9;
        float t = 0.f;
#pragma unroll
        for (int g2 = 0; g2 < 8; ++g2) t += sred[(g2 * WO_ + wo2) * 9 + k];
        atomicAdd(&scores[((size_t)nho * WO_ + wo2) * 9 + k], t * (1.f / 3.f));
    }
}

// ---- kernel 2: softmax over k=9, in place ----
__global__ __launch_bounds__(256)
void softmax_kernel(float* __restrict__ scores) {
    int p = blockIdx.x * 256 + threadIdx.x;
    if (p >= NPIX) return;
    float* s = scores + (size_t)p * 9;
    float v[9];
#pragma unroll
    for (int k = 0; k < 9; ++k) v[k] = s[k];
    float m = v[0];
#pragma unroll
    for (int k = 1; k < 9; ++k) m = fmaxf(m, v[k]);
    float d = 0.f;
#pragma unroll
    for (int k = 0; k < 9; ++k) { v[k] = __expf(v[k] - m); d += v[k]; }
    float inv = 1.f / d;
#pragma unroll
    for (int k = 0; k < 9; ++k) s[k] = v[k] * inv;
}

// ---- kernel 3: merge. one block per (n,c) plane ----
constexpr int K3_TW = 58;                      // rows 0..57 (ghost top at 0), cols 0..55 data

__global__ __launch_bounds__(256)
void merge_kernel(const float* __restrict__ x, const float* __restrict__ attn,
                  float* __restrict__ out) {
    __shared__ float tile_raw[4 + K3_TW * K3_TW];
    float* tile = tile_raw + 4;

    const int tid = threadIdx.x;
    const int blk = blockIdx.x;
    const int n   = blk / C_;                  // consecutive blocks share n -> attn L2-hot
    const int c   = blk - n * C_;

    for (int i = tid; i < 4 + K3_TW * K3_TW; i += 256) tile_raw[i] = 0.f;
    __syncthreads();

    const float* xp = x + ((size_t)n * C_ + c) * (H_ * W_);
    // 56 rows x 14 float4; input row r -> tile row r+1 (ghost top row 0 stays zero)
    for (int i = tid; i < 784; i += 256) {
        int r  = i / 14;
        int kk = i - r * 14;
        float4 v = *(const float4*)(xp + (size_t)r * W_ + 4 * kk);
        float* d = &tile[(r + 1) * K3_TW + 4 * kk];
        d[0] = v.x; d[1] = v.y; d[2] = v.z; d[3] = v.w;
    }
    __syncthreads();

    float* op = out + ((size_t)n * C_ + c) * (HO_ * WO_);
    const float* ap = attn + (size_t)n * (HO_ * WO_) * 9;
    for (int p = tid; p < HO_ * WO_; p += 256) {
        int ho = p / WO_, wo = p - ho * WO_;
        const float* a  = &ap[(size_t)p * 9];
        // window rows 2ho-1..2ho+1 -> tile rows 2ho..2ho+2; cols 2wo-1..2wo+1 -> tile cols 2wo-1..
        const float* tp = &tile[(size_t)(2 * ho) * K3_TW + 2 * wo - 1];
        float y = a[0] * tp[0]           + a[1] * tp[1]            + a[2] * tp[2]
                + a[3] * tp[K3_TW]       + a[4] * tp[K3_TW + 1]    + a[5] * tp[K3_TW + 2]
                + a[6] * tp[2 * K3_TW]   + a[7] * tp[2 * K3_TW + 1] + a[8] * tp[2 * K3_TW + 2];
        op[p] = y;
    }
}

extern "C" void kernel_launch(void* const* d_in, const int* in_sizes, int n_in,
                              void* d_out, int out_size, void* d_ws, size_t ws_size,
                              hipStream_t stream) {
    const float* x   = (const float*)d_in[0];
    float* out       = (float*)d_out;
    float* scores    = (float*)d_ws;           // NPIX*9 floats = 903168 B

    hipMemsetAsync(d_ws, 0, (size_t)NPIX * 9 * sizeof(float), stream);
    scores_kernel<<<dim3(K1_NCHUNK * N_ * HO_), dim3(256), 0, stream>>>(x, scores);
    softmax_kernel<<<dim3((NPIX + 255) / 256), dim3(256), 0, stream>>>(scores);
    merge_kernel<<<dim3(N_ * C_), dim3(256), 0, stream>>>(x, scores, out);
}